// Round 1
// baseline (176.617 us; speedup 1.0000x reference)
//
#include <hip/hip_runtime.h>

// Problem constants (from reference): N=512, S=64, C=1024, B=10, PAD=0, NEG=-1e9
#define NN 512
#define SS 64
#define CC 1024
#define BB 10

// One block per (n,s). 256 threads, each owns 4 classes.
__global__ __launch_bounds__(256) void spop_kernel(
    const int* __restrict__ ban_ids,   // [N,S,B]
    const int* __restrict__ item_ids,  // [N,S]
    float* __restrict__ out_pi,        // [N,S,C]
    float* __restrict__ out_v)         // [N,S]
{
    const int b   = blockIdx.x;        // n*S + s
    const int n   = b >> 6;            // / SS
    const int tid = threadIdx.x;
    const int lane = tid & 63;
    const int wid  = tid >> 6;

    __shared__ __align__(16) float cnt[CC];
    __shared__ int   bans[BB];
    __shared__ float red_m[4];
    __shared__ float red_s[4];

    // Zero the histogram (1024 floats / 256 threads = 4 each)
#pragma unroll
    for (int k = 0; k < 4; ++k) cnt[tid + 256 * k] = 0.0f;
    if (tid < BB) bans[tid] = ban_ids[b * BB + tid];
    __syncthreads();

    // Wave 0 builds the per-row histogram.
    // w[s] = 1 iff item != PAD and s is not the LAST non-pad position.
    if (tid < 64) {
        int id = item_ids[n * SS + tid];
        bool nonpad = (id != 0);
        unsigned long long m = __ballot(nonpad);   // 64-bit wave mask
        // last non-pad position = 63 - clz(m). m==0 -> nonpad is false anyway;
        // OR with 1 to keep clz well-defined.
        int last = 63 - __clzll(m | 1ull);
        if (nonpad && tid != last) atomicAdd(&cnt[id], 1.0f);
    }
    __syncthreads();

    // Each thread: 4 consecutive classes.
    const int c0 = tid * 4;
    float4 vv = *reinterpret_cast<const float4*>(&cnt[c0]);
    float v0 = vv.x, v1 = vv.y, v2 = vv.z, v3 = vv.w;

    // Ban mask (.set semantics -> banned logit = count - 1e9, duplicates ok)
    bool m0 = false, m1 = false, m2 = false, m3 = false;
#pragma unroll
    for (int j = 0; j < BB; ++j) {
        int bj = bans[j];   // LDS broadcast (same address, conflict-free)
        m0 |= (bj == c0);
        m1 |= (bj == c0 + 1);
        m2 |= (bj == c0 + 2);
        m3 |= (bj == c0 + 3);
    }
    if (m0) v0 -= 1e9f;
    if (m1) v1 -= 1e9f;
    if (m2) v2 -= 1e9f;
    if (m3) v3 -= 1e9f;

    // --- block reduce: max ---
    float mx = fmaxf(fmaxf(v0, v1), fmaxf(v2, v3));
#pragma unroll
    for (int off = 32; off >= 1; off >>= 1)
        mx = fmaxf(mx, __shfl_down(mx, off));
    if (lane == 0) red_m[wid] = mx;
    __syncthreads();
    mx = fmaxf(fmaxf(red_m[0], red_m[1]), fmaxf(red_m[2], red_m[3]));

    // --- block reduce: sum of exp ---
    float se = __expf(v0 - mx) + __expf(v1 - mx) + __expf(v2 - mx) + __expf(v3 - mx);
#pragma unroll
    for (int off = 32; off >= 1; off >>= 1)
        se += __shfl_down(se, off);
    if (lane == 0) red_s[wid] = se;
    __syncthreads();
    se = red_s[0] + red_s[1] + red_s[2] + red_s[3];

    const float lse = mx + __logf(se);

    float4 o;
    o.x = v0 - lse;
    o.y = v1 - lse;
    o.z = v2 - lse;
    o.w = v3 - lse;
    *reinterpret_cast<float4*>(&out_pi[(size_t)b * CC + c0]) = o;

    // v = zeros [N,S,1]; d_out is poisoned before timed runs, so write it.
    if (tid == 0) out_v[b] = 0.0f;
}

extern "C" void kernel_launch(void* const* d_in, const int* in_sizes, int n_in,
                              void* d_out, int out_size, void* d_ws, size_t ws_size,
                              hipStream_t stream) {
    // inputs: d_in[0] = null_w (fp32, unused), d_in[1] = ban_ids (int32 [N,S,B]),
    //         d_in[2] = item_ids (int32 [N,S])
    const int* ban_ids  = (const int*)d_in[1];
    const int* item_ids = (const int*)d_in[2];
    float* out_pi = (float*)d_out;                       // [N,S,C] flat first
    float* out_v  = out_pi + (size_t)NN * SS * CC;       // then [N,S]

    spop_kernel<<<dim3(NN * SS), dim3(256), 0, stream>>>(ban_ids, item_ids, out_pi, out_v);
}

// Round 2
// 157.174 us; speedup vs baseline: 1.1237x; 1.1237x over previous
//
#include <hip/hip_runtime.h>

// N=512, S=64, C=1024, B=10, PAD=0, NEG=-1e9
#define NN 512
#define SS 64
#define CC 1024
#define BB 10

// ---------------- Kernel 1: per-row stats (one block of 64 = one row n) ------
// counts[n,c], rowmax[n], rowsumexp[n] = sum_c exp(counts[n,c] - rowmax[n])
__global__ __launch_bounds__(64) void row_stats_kernel(
    const int* __restrict__ item_ids,   // [N,S]
    float* __restrict__ counts,         // ws: [N,C]
    float* __restrict__ rowstat)        // ws: [N,2] (max, sumexp)
{
    const int n = blockIdx.x;
    const int lane = threadIdx.x;       // 0..63

    __shared__ __align__(16) float cnt[CC];

    // zero histogram: 16 floats per lane
#pragma unroll
    for (int k = 0; k < 4; ++k)
        *reinterpret_cast<float4*>(&cnt[k * 256 + lane * 4]) = make_float4(0.f, 0.f, 0.f, 0.f);
    __syncthreads();

    int id = item_ids[n * SS + lane];
    bool nonpad = (id != 0);
    unsigned long long m = __ballot(nonpad);
    int last = 63 - __clzll(m | 1ull);
    if (nonpad && lane != last) atomicAdd(&cnt[id], 1.0f);
    __syncthreads();

    // read back 16 values per lane, reduce max
    float4 r[4];
    float mx = -1.0f;
#pragma unroll
    for (int k = 0; k < 4; ++k) {
        r[k] = *reinterpret_cast<const float4*>(&cnt[k * 256 + lane * 4]);
        mx = fmaxf(mx, fmaxf(fmaxf(r[k].x, r[k].y), fmaxf(r[k].z, r[k].w)));
    }
#pragma unroll
    for (int off = 32; off >= 1; off >>= 1)
        mx = fmaxf(mx, __shfl_xor(mx, off));
    // sum exp(c - mx)
    float se = 0.f;
#pragma unroll
    for (int k = 0; k < 4; ++k)
        se += __expf(r[k].x - mx) + __expf(r[k].y - mx) +
              __expf(r[k].z - mx) + __expf(r[k].w - mx);
#pragma unroll
    for (int off = 32; off >= 1; off >>= 1)
        se += __shfl_xor(se, off);

    // write counts row to global ws
#pragma unroll
    for (int k = 0; k < 4; ++k)
        *reinterpret_cast<float4*>(&counts[(size_t)n * CC + k * 256 + lane * 4]) = r[k];
    if (lane == 0) { rowstat[n * 2] = mx; rowstat[n * 2 + 1] = se; }
}

// ---------------- Kernel 2: streaming output (1 wave per (n,s)) --------------
__global__ __launch_bounds__(256) void write_pi_kernel(
    const int* __restrict__ ban_ids,    // [N,S,B]
    const float* __restrict__ counts,   // [N,C]
    const float* __restrict__ rowstat,  // [N,2]
    float* __restrict__ out_pi,         // [N,S,C]
    float* __restrict__ out_v)          // [N,S]
{
    const int tid  = threadIdx.x;
    const int lane = tid & 63;
    const int b    = blockIdx.x * 4 + (tid >> 6);   // (n,s) index
    const int n    = b >> 6;

    // load bans (same addresses across the wave -> L1 broadcast)
    int ban[BB];
#pragma unroll
    for (int j = 0; j < BB; ++j) ban[j] = ban_ids[b * BB + j];

    const float mx     = rowstat[n * 2];
    const float sumall = rowstat[n * 2 + 1];

    // banned exp-sum over DISTINCT ban ids (scatter .set semantics)
    float bsum = 0.f;
#pragma unroll
    for (int j = 0; j < BB; ++j) {
        bool dup = false;
#pragma unroll
        for (int k = 0; k < BB; ++k)
            if (k < j) dup |= (ban[k] == ban[j]);
        if (!dup) bsum += __expf(counts[(size_t)n * CC + ban[j]] - mx);
    }
    float valid = sumall - bsum;
    valid = fmaxf(valid, 1e-30f);            // guard against cancellation -> -inf
    const float lse = mx + __logf(valid);

    // per-lane 16-bit banned mask: class c is banned & owned by this lane iff
    // ((c>>2)&63)==lane; bit index = ((c>>8)<<2) | (c&3)
    unsigned bmask = 0;
#pragma unroll
    for (int j = 0; j < BB; ++j) {
        int c = ban[j];
        if (((c >> 2) & 63) == lane)
            bmask |= 1u << (((c >> 8) << 2) | (c & 3));
    }

    const float4* crow = reinterpret_cast<const float4*>(&counts[(size_t)n * CC]);
    float4* orow = reinterpret_cast<float4*>(&out_pi[(size_t)b * CC]);

#pragma unroll
    for (int chunk = 0; chunk < 4; ++chunk) {
        const int idx4 = chunk * 64 + lane;          // float4 index within row
        float4 v = crow[idx4];
        const int mb = chunk * 4;
        if (bmask & (1u << (mb + 0))) v.x -= 1e9f;
        if (bmask & (1u << (mb + 1))) v.y -= 1e9f;
        if (bmask & (1u << (mb + 2))) v.z -= 1e9f;
        if (bmask & (1u << (mb + 3))) v.w -= 1e9f;
        v.x -= lse; v.y -= lse; v.z -= lse; v.w -= lse;
        orow[idx4] = v;
    }

    if (lane == 0) out_v[b] = 0.0f;
}

extern "C" void kernel_launch(void* const* d_in, const int* in_sizes, int n_in,
                              void* d_out, int out_size, void* d_ws, size_t ws_size,
                              hipStream_t stream) {
    const int* ban_ids  = (const int*)d_in[1];
    const int* item_ids = (const int*)d_in[2];
    float* out_pi = (float*)d_out;                      // [N,S,C]
    float* out_v  = out_pi + (size_t)NN * SS * CC;      // [N,S]

    float* counts  = (float*)d_ws;                      // [N,C] = 2 MB
    float* rowstat = counts + (size_t)NN * CC;          // [N,2]

    row_stats_kernel<<<dim3(NN), dim3(64), 0, stream>>>(item_ids, counts, rowstat);
    write_pi_kernel<<<dim3(NN * SS / 4), dim3(256), 0, stream>>>(
        ban_ids, counts, rowstat, out_pi, out_v);
}

// Round 3
// 156.520 us; speedup vs baseline: 1.1284x; 1.0042x over previous
//
#include <hip/hip_runtime.h>

// N=512, S=64, C=1024, B=10, PAD=0, NEG=-1e9
#define NN 512
#define SS 64
#define CC 1024
#define BB 10

typedef float nfloat4 __attribute__((ext_vector_type(4)));

// ---------------- Kernel 1: per-row stats (one wave = one row n) -------------
__global__ __launch_bounds__(64) void row_stats_kernel(
    const int* __restrict__ item_ids,   // [N,S]
    float* __restrict__ counts,         // ws: [N,C]
    float* __restrict__ rowstat)        // ws: [N,2] (max, sumexp)
{
    const int n = blockIdx.x;
    const int lane = threadIdx.x;       // 0..63

    __shared__ __align__(16) float cnt[CC];

#pragma unroll
    for (int k = 0; k < 4; ++k)
        *reinterpret_cast<float4*>(&cnt[k * 256 + lane * 4]) = make_float4(0.f, 0.f, 0.f, 0.f);
    __syncthreads();

    int id = item_ids[n * SS + lane];
    bool nonpad = (id != 0);
    unsigned long long m = __ballot(nonpad);
    int last = 63 - __clzll(m | 1ull);
    if (nonpad && lane != last) atomicAdd(&cnt[id], 1.0f);
    __syncthreads();

    float4 r[4];
    float mx = -1.0f;
#pragma unroll
    for (int k = 0; k < 4; ++k) {
        r[k] = *reinterpret_cast<const float4*>(&cnt[k * 256 + lane * 4]);
        mx = fmaxf(mx, fmaxf(fmaxf(r[k].x, r[k].y), fmaxf(r[k].z, r[k].w)));
    }
#pragma unroll
    for (int off = 32; off >= 1; off >>= 1)
        mx = fmaxf(mx, __shfl_xor(mx, off));
    float se = 0.f;
#pragma unroll
    for (int k = 0; k < 4; ++k)
        se += __expf(r[k].x - mx) + __expf(r[k].y - mx) +
              __expf(r[k].z - mx) + __expf(r[k].w - mx);
#pragma unroll
    for (int off = 32; off >= 1; off >>= 1)
        se += __shfl_xor(se, off);

#pragma unroll
    for (int k = 0; k < 4; ++k)
        *reinterpret_cast<float4*>(&counts[(size_t)n * CC + k * 256 + lane * 4]) = r[k];
    if (lane == 0) { rowstat[n * 2] = mx; rowstat[n * 2 + 1] = se; }
}

// ---------------- Kernel 2: streaming output (1 wave = 2 (n,s) rows) ---------
__global__ __launch_bounds__(256) void write_pi_kernel(
    const int* __restrict__ ban_ids,    // [N,S,B]
    const float* __restrict__ counts,   // [N,C]
    const float* __restrict__ rowstat,  // [N,2]
    float* __restrict__ out_pi,         // [N,S,C]
    float* __restrict__ out_v)          // [N,S]
{
    const int tid  = threadIdx.x;
    const int lane = tid & 63;
    const int wid  = tid >> 6;
    const int bp   = blockIdx.x * 4 + wid;  // pair index
    const int b0   = bp * 2;                // first (n,s); b0 even -> b0,b0+1 share n
    const int n    = b0 >> 6;

    // Issue the count-row loads first (overlaps the prologue gathers below).
    const float4* crow = reinterpret_cast<const float4*>(&counts[(size_t)n * CC]);
    float4 c[4];
#pragma unroll
    for (int ch = 0; ch < 4; ++ch) c[ch] = crow[ch * 64 + lane];

    const float mx     = rowstat[n * 2];
    const float sumall = rowstat[n * 2 + 1];

    float    lse[2];
    unsigned bm[2];
#pragma unroll
    for (int r = 0; r < 2; ++r) {
        const int b = b0 + r;
        int ban[BB];
#pragma unroll
        for (int j = 0; j < BB; ++j) ban[j] = ban_ids[b * BB + j];

        // banned exp-sum over DISTINCT ban ids (.set semantics)
        float bsum = 0.f;
#pragma unroll
        for (int j = 0; j < BB; ++j) {
            bool dup = false;
#pragma unroll
            for (int k = 0; k < BB; ++k)
                if (k < j) dup |= (ban[k] == ban[j]);
            if (!dup) bsum += __expf(counts[(size_t)n * CC + ban[j]] - mx);
        }
        float valid = fmaxf(sumall - bsum, 1e-30f);
        lse[r] = mx + __logf(valid);

        // per-lane 16-bit banned mask: class c owned by this lane iff ((c>>2)&63)==lane
        unsigned msk = 0;
#pragma unroll
        for (int j = 0; j < BB; ++j) {
            int cc = ban[j];
            if (((cc >> 2) & 63) == lane)
                msk |= 1u << (((cc >> 8) << 2) | (cc & 3));
        }
        bm[r] = msk;
    }

#pragma unroll
    for (int r = 0; r < 2; ++r) {
        float* orow = &out_pi[(size_t)(b0 + r) * CC];
#pragma unroll
        for (int ch = 0; ch < 4; ++ch) {
            float4 v = c[ch];
            const int mb = ch * 4;
            if (bm[r] & (1u << (mb + 0))) v.x -= 1e9f;
            if (bm[r] & (1u << (mb + 1))) v.y -= 1e9f;
            if (bm[r] & (1u << (mb + 2))) v.z -= 1e9f;
            if (bm[r] & (1u << (mb + 3))) v.w -= 1e9f;
            v.x -= lse[r]; v.y -= lse[r]; v.z -= lse[r]; v.w -= lse[r];
            nfloat4 nv = { v.x, v.y, v.z, v.w };
            __builtin_nontemporal_store(nv,
                reinterpret_cast<nfloat4*>(orow) + ch * 64 + lane);
        }
    }

    if (lane < 2) out_v[b0 + lane] = 0.0f;
}

extern "C" void kernel_launch(void* const* d_in, const int* in_sizes, int n_in,
                              void* d_out, int out_size, void* d_ws, size_t ws_size,
                              hipStream_t stream) {
    const int* ban_ids  = (const int*)d_in[1];
    const int* item_ids = (const int*)d_in[2];
    float* out_pi = (float*)d_out;                      // [N,S,C]
    float* out_v  = out_pi + (size_t)NN * SS * CC;      // [N,S]

    float* counts  = (float*)d_ws;                      // [N,C] = 2 MB
    float* rowstat = counts + (size_t)NN * CC;          // [N,2]

    row_stats_kernel<<<dim3(NN), dim3(64), 0, stream>>>(item_ids, counts, rowstat);
    write_pi_kernel<<<dim3(NN * SS / 8), dim3(256), 0, stream>>>(
        ban_ids, counts, rowstat, out_pi, out_v);
}

// Round 4
// 147.433 us; speedup vs baseline: 1.1979x; 1.0616x over previous
//
#include <hip/hip_runtime.h>

// N=512, S=64, C=1024, B=10, PAD=0, NEG=-1e9
#define NN 512
#define SS 64
#define CC 1024
#define BB 10
#define SH 32              // s-values per block (half a row)

typedef float nfloat4 __attribute__((ext_vector_type(4)));

// One block = (n, half-of-s). 256 threads. Fully fused.
__global__ __launch_bounds__(256) void spop_fused_kernel(
    const int* __restrict__ ban_ids,    // [N,S,B]
    const int* __restrict__ item_ids,   // [N,S]
    float* __restrict__ out_pi,         // [N,S,C]
    float* __restrict__ out_v)          // [N,S]
{
    const int tid  = threadIdx.x;
    const int lane = tid & 63;
    const int wid  = tid >> 6;
    const int n    = blockIdx.x >> 1;
    const int s0   = (blockIdx.x & 1) * SH;
    const int b0   = n * SS + s0;               // first (n,s) this block owns

    __shared__ __align__(16) float cnt[CC];     // 4 KB histogram
    __shared__ unsigned mask[SH][CC / 32];      // 4 KB: 1024-bit ban mask per s
    __shared__ int   bansh[SH * BB];            // 1.25 KB cached ban ids
    __shared__ float lse_s[SH];
    __shared__ float red_m[4], red_s[4];

    // ---- zero LDS ----
    *reinterpret_cast<float4*>(&cnt[tid * 4]) = make_float4(0.f, 0.f, 0.f, 0.f);
#pragma unroll
    for (int k = 0; k < 4; ++k) mask[0][tid + 256 * k] = 0u;   // flat 1024 words
    __syncthreads();

    // ---- histogram (wave 0 only) ----
    if (tid < 64) {
        int id = item_ids[n * SS + tid];
        bool nonpad = (id != 0);
        unsigned long long m = __ballot(nonpad);
        int last = 63 - __clzll(m | 1ull);
        if (nonpad && tid != last) atomicAdd(&cnt[id], 1.0f);
    }
    __syncthreads();

    // ---- each thread owns 4 classes; block-reduce max then sumexp ----
    const float4 c4 = *reinterpret_cast<const float4*>(&cnt[tid * 4]);

    float mx = fmaxf(fmaxf(c4.x, c4.y), fmaxf(c4.z, c4.w));
#pragma unroll
    for (int off = 32; off >= 1; off >>= 1)
        mx = fmaxf(mx, __shfl_xor(mx, off));
    if (lane == 0) red_m[wid] = mx;

    // ---- ban scatter: 32 s * 10 bans = 320 contiguous loads ----
    // (overlaps the reduction barriers)
    for (int i = tid; i < SH * BB; i += 256) {
        int c = ban_ids[b0 * BB + i];           // == ban_ids[n, s0 + i/10, i%10]
        bansh[i] = c;
        atomicOr(&mask[i / BB][c >> 5], 1u << (c & 31));
    }
    __syncthreads();
    mx = fmaxf(fmaxf(red_m[0], red_m[1]), fmaxf(red_m[2], red_m[3]));

    float se = __expf(c4.x - mx) + __expf(c4.y - mx) +
               __expf(c4.z - mx) + __expf(c4.w - mx);
#pragma unroll
    for (int off = 32; off >= 1; off >>= 1)
        se += __shfl_xor(se, off);
    if (lane == 0) red_s[wid] = se;
    __syncthreads();
    const float sumall = red_s[0] + red_s[1] + red_s[2] + red_s[3];

    // ---- per-s lse (threads 0..31, one s each) ----
    if (tid < SH) {
        int ban[BB];
#pragma unroll
        for (int j = 0; j < BB; ++j) ban[j] = bansh[tid * BB + j];
        float bsum = 0.f;
#pragma unroll
        for (int j = 0; j < BB; ++j) {
            bool dup = false;
#pragma unroll
            for (int k = 0; k < BB; ++k)
                if (k < j) dup |= (ban[k] == ban[j]);
            if (!dup) bsum += __expf(cnt[ban[j]] - mx);
        }
        float valid = fmaxf(sumall - bsum, 1e-30f);
        lse_s[tid] = mx + __logf(valid);
        out_v[b0 + tid] = 0.0f;                 // v = zeros
    }
    __syncthreads();

    // ---- streaming epilogue: one 4 KB row per iteration ----
    const int mword = tid >> 3;                 // (tid*4)>>5
    const int msh   = (tid & 7) * 4;
    nfloat4* obase = reinterpret_cast<nfloat4*>(&out_pi[(size_t)b0 * CC]) + tid;

    for (int s = 0; s < SH; ++s) {
        const float l = lse_s[s];               // LDS broadcast
        const unsigned m4 = (mask[s][mword] >> msh) & 0xF;
        float4 v = c4;
        if (m4 & 1u) v.x -= 1e9f;
        if (m4 & 2u) v.y -= 1e9f;
        if (m4 & 4u) v.z -= 1e9f;
        if (m4 & 8u) v.w -= 1e9f;
        nfloat4 nv = { v.x - l, v.y - l, v.z - l, v.w - l };
        __builtin_nontemporal_store(nv, obase + (size_t)s * (CC / 4));
    }
}

extern "C" void kernel_launch(void* const* d_in, const int* in_sizes, int n_in,
                              void* d_out, int out_size, void* d_ws, size_t ws_size,
                              hipStream_t stream) {
    const int* ban_ids  = (const int*)d_in[1];
    const int* item_ids = (const int*)d_in[2];
    float* out_pi = (float*)d_out;                      // [N,S,C]
    float* out_v  = out_pi + (size_t)NN * SS * CC;      // [N,S]

    spop_fused_kernel<<<dim3(NN * (SS / SH)), dim3(256), 0, stream>>>(
        ban_ids, item_ids, out_pi, out_v);
}

// Round 5
// 146.207 us; speedup vs baseline: 1.2080x; 1.0084x over previous
//
#include <hip/hip_runtime.h>

// N=512, S=64, C=1024, B=10, PAD=0, NEG=-1e9
#define NN 512
#define SS 64
#define CC 1024
#define BB 10
#define SH 32              // s-values per block (half a row)

typedef float nfloat4 __attribute__((ext_vector_type(4)));

// One block = (n, half-of-s). 256 threads. Fully fused.
__global__ __launch_bounds__(256) void spop_fused_kernel(
    const int* __restrict__ ban_ids,    // [N,S,B]
    const int* __restrict__ item_ids,   // [N,S]
    float* __restrict__ out_pi,         // [N,S,C]
    float* __restrict__ out_v)          // [N,S]
{
    const int tid  = threadIdx.x;
    const int lane = tid & 63;
    const int wid  = tid >> 6;
    const int n    = blockIdx.x >> 1;
    const int s0   = (blockIdx.x & 1) * SH;
    const int b0   = n * SS + s0;               // first (n,s) this block owns

    __shared__ __align__(16) float cnt[CC];     // 4 KB histogram
    __shared__ unsigned mask[SH][CC / 32];      // 4 KB: 1024-bit ban mask per s
    __shared__ int   bansh[SH * BB];            // 1.25 KB cached ban ids
    __shared__ float lse_s[SH];
    __shared__ float red_m[4], red_s[4];

    // ---- zero LDS ----
    *reinterpret_cast<float4*>(&cnt[tid * 4]) = make_float4(0.f, 0.f, 0.f, 0.f);
#pragma unroll
    for (int k = 0; k < 4; ++k) mask[0][tid + 256 * k] = 0u;   // flat 1024 words
    __syncthreads();

    // ---- histogram (wave 0 only) ----
    if (tid < 64) {
        int id = item_ids[n * SS + tid];
        bool nonpad = (id != 0);
        unsigned long long m = __ballot(nonpad);
        int last = 63 - __clzll(m | 1ull);
        if (nonpad && tid != last) atomicAdd(&cnt[id], 1.0f);
    }
    __syncthreads();

    // ---- each thread owns 4 classes; block-reduce max then sumexp ----
    const float4 c4 = *reinterpret_cast<const float4*>(&cnt[tid * 4]);

    float mx = fmaxf(fmaxf(c4.x, c4.y), fmaxf(c4.z, c4.w));
#pragma unroll
    for (int off = 32; off >= 1; off >>= 1)
        mx = fmaxf(mx, __shfl_xor(mx, off));
    if (lane == 0) red_m[wid] = mx;

    // ---- ban scatter: 32 s * 10 bans = 320 contiguous loads ----
    for (int i = tid; i < SH * BB; i += 256) {
        int c = ban_ids[b0 * BB + i];           // == ban_ids[n, s0 + i/10, i%10]
        bansh[i] = c;
        atomicOr(&mask[i / BB][c >> 5], 1u << (c & 31));
    }
    __syncthreads();
    mx = fmaxf(fmaxf(red_m[0], red_m[1]), fmaxf(red_m[2], red_m[3]));

    float se = __expf(c4.x - mx) + __expf(c4.y - mx) +
               __expf(c4.z - mx) + __expf(c4.w - mx);
#pragma unroll
    for (int off = 32; off >= 1; off >>= 1)
        se += __shfl_xor(se, off);
    if (lane == 0) red_s[wid] = se;
    __syncthreads();
    const float sumall = red_s[0] + red_s[1] + red_s[2] + red_s[3];

    // ---- per-s lse (threads 0..31, one s each) ----
    if (tid < SH) {
        int ban[BB];
#pragma unroll
        for (int j = 0; j < BB; ++j) ban[j] = bansh[tid * BB + j];
        float bsum = 0.f;
#pragma unroll
        for (int j = 0; j < BB; ++j) {
            bool dup = false;
#pragma unroll
            for (int k = 0; k < BB; ++k)
                if (k < j) dup |= (ban[k] == ban[j]);
            if (!dup) bsum += __expf(cnt[ban[j]] - mx);
        }
        float valid = fmaxf(sumall - bsum, 1e-30f);
        lse_s[tid] = mx + __logf(valid);
        out_v[b0 + tid] = 0.0f;                 // v = zeros
    }
    __syncthreads();

    // ---- streaming epilogue ----
    // Hoist ALL LDS reads (conflict-free: lse is a 64-lane broadcast, mask is
    // 8-lane broadcast groups over 8 distinct banks), then burst 32
    // back-to-back nontemporal stores with no lgkmcnt in the chain.
    const int mword = tid >> 3;                 // (tid*4)>>5
    const int msh   = (tid & 7) * 4;
    nfloat4* obase = reinterpret_cast<nfloat4*>(&out_pi[(size_t)b0 * CC]) + tid;

    float    lse_r[SH];
    unsigned m4_r[SH];
#pragma unroll
    for (int s = 0; s < SH; ++s) {
        lse_r[s] = lse_s[s];
        m4_r[s]  = (mask[s][mword] >> msh) & 0xF;
    }

#pragma unroll
    for (int s = 0; s < SH; ++s) {
        const float l = lse_r[s];
        const unsigned m4 = m4_r[s];
        float4 v = c4;
        if (m4 & 1u) v.x -= 1e9f;
        if (m4 & 2u) v.y -= 1e9f;
        if (m4 & 4u) v.z -= 1e9f;
        if (m4 & 8u) v.w -= 1e9f;
        nfloat4 nv = { v.x - l, v.y - l, v.z - l, v.w - l };
        __builtin_nontemporal_store(nv, obase + (size_t)s * (CC / 4));
    }
}

extern "C" void kernel_launch(void* const* d_in, const int* in_sizes, int n_in,
                              void* d_out, int out_size, void* d_ws, size_t ws_size,
                              hipStream_t stream) {
    const int* ban_ids  = (const int*)d_in[1];
    const int* item_ids = (const int*)d_in[2];
    float* out_pi = (float*)d_out;                      // [N,S,C]
    float* out_v  = out_pi + (size_t)NN * SS * CC;      // [N,S]

    spop_fused_kernel<<<dim3(NN * (SS / SH)), dim3(256), 0, stream>>>(
        ban_ids, item_ids, out_pi, out_v);
}